// Round 15
// baseline (304.975 us; speedup 1.0000x reference)
//
#include <hip/hip_runtime.h>
#include <hip/hip_bf16.h>
#include <hip/hip_cooperative_groups.h>

namespace cg = cooperative_groups;

#define B 64
#define T 50
#define S 400
#define H 512
#define E 256
#define V 50000
#define EXT 50250
#define G3 1536
#define NCH 16
#define NCE 8
#define TGRID 1024

typedef __attribute__((ext_vector_type(8))) short short8;
typedef __attribute__((ext_vector_type(4))) float f32x4;

// ---- output offsets (f32 elements, return order) ----
#define O_PFINAL 0L
#define O_PGEN   3216000L
#define O_PVOCAB 3216064L
#define O_ATT    6416064L
#define O_DECH   6441664L
#define O_H      8112832L
#define O_NPA    8145600L

// ---- workspace offsets (f32 elements); ws = 256 MB ----
#define OFF_G      0L        /* B*G3 = 98304 */
#define OFF_GG     98304L    /* B*G3 */
#define OFF_ENCP   196608L   /* B*NCE*H = 262144 */
#define OFF_DEC    458752L   /* B*H */
#define OFF_E      491520L   /* B*S */
#define OFF_ESUM   517120L   /* B*NCE */
#define OFF_PG     517632L   /* 64 */
#define OFF_PROJBF 517696L   /* 16384 bf16 = 8192 f32 */
#define OFF_PSUM   525888L   /* B*NCH = 1024 */
#define OFF_TOK    1048576L  /* B*EXT f32 */

__device__ __forceinline__ float sigmoidf_(float x){ return 1.0f/(1.0f+expf(-x)); }
__device__ __forceinline__ short f2bs(float x){
    union { __hip_bfloat16 b; short s; } c; c.b = __float2bfloat16(x); return c.s;
}
__device__ __forceinline__ short8 cvt8(const float* p){
    f32x4 w0 = *(const f32x4*)p;
    f32x4 w1 = *(const f32x4*)(p + 4);
    short8 r;
    r[0]=f2bs(w0[0]); r[1]=f2bs(w0[1]); r[2]=f2bs(w0[2]); r[3]=f2bs(w0[3]);
    r[4]=f2bs(w1[0]); r[5]=f2bs(w1[1]); r[6]=f2bs(w1[2]); r[7]=f2bs(w1[3]);
    return r;
}
// swizzled projbf index (A-fragment order, bijective on [0,16384))
__device__ __forceinline__ int pb_idx(int b, int e){
    return ((((b >> 4)*8 + (e >> 5))*4 + ((e >> 3) & 3))*16 + (b & 15))*8 + (e & 7);
}
__device__ __forceinline__ float gru_h(const float* g, const float* Gg,
                                       const float* lh, int b, int k){
    float ir = g [b*G3 + k], iz = g [b*G3 + H + k], inn = g [b*G3 + 2*H + k];
    float hr = Gg[b*G3 + k], hz = Gg[b*G3 + H + k], hn  = Gg[b*G3 + 2*H + k];
    float r = sigmoidf_(ir + hr), z = sigmoidf_(iz + hz);
    float n = tanhf(inn + r*hn);
    return (1.f - z)*n + z*lh[b*H + k];
}

// ---------------- K1: front = gates MFMA (blk<96) | copies+zero (blk>=96) ----------------
__global__ void __launch_bounds__(256) k_front(const int* tok,
                        const float* emb, const float* lh,
                        const float* Wih, const float* Whh,
                        const float* bih, const float* bhh,
                        const float* pdh, const float* pa,
                        float* g, float* Gg, float* out, float* tokd){
    if (blockIdx.x < 96){
        if (threadIdx.x >= 128) return;
        int lane = threadIdx.x & 63, wave = threadIdx.x >> 6;
        int row = lane & 15, kg = lane >> 4;
        int j = blockIdx.x*16 + row;
        f32x4 c0={0.f,0.f,0.f,0.f}, c1={0.f,0.f,0.f,0.f};
        f32x4 c2={0.f,0.f,0.f,0.f}, c3={0.f,0.f,0.f,0.f};
        if (wave == 0){
            const float* Wp = Wih + (long)j*E + kg*8;
            const float* a0p = emb + (long)tok[row     ]*E + kg*8;
            const float* a1p = emb + (long)tok[row + 16]*E + kg*8;
            const float* a2p = emb + (long)tok[row + 32]*E + kg*8;
            const float* a3p = emb + (long)tok[row + 48]*E + kg*8;
            #pragma unroll
            for (int ks = 0; ks < 8; ks++){
                short8 bb = cvt8(Wp + ks*32);
                c0 = __builtin_amdgcn_mfma_f32_16x16x32_bf16(cvt8(a0p + ks*32), bb, c0, 0, 0, 0);
                c1 = __builtin_amdgcn_mfma_f32_16x16x32_bf16(cvt8(a1p + ks*32), bb, c1, 0, 0, 0);
                c2 = __builtin_amdgcn_mfma_f32_16x16x32_bf16(cvt8(a2p + ks*32), bb, c2, 0, 0, 0);
                c3 = __builtin_amdgcn_mfma_f32_16x16x32_bf16(cvt8(a3p + ks*32), bb, c3, 0, 0, 0);
            }
            float bi = bih[j];
            #pragma unroll
            for (int r = 0; r < 4; r++){
                int bg = kg*4 + r;
                g[(long)(bg     )*G3 + j] = c0[r] + bi;
                g[(long)(bg + 16)*G3 + j] = c1[r] + bi;
                g[(long)(bg + 32)*G3 + j] = c2[r] + bi;
                g[(long)(bg + 48)*G3 + j] = c3[r] + bi;
            }
        } else {
            const float* Wp = Whh + (long)j*H + kg*8;
            const float* a0p = lh + (long)(row     )*H + kg*8;
            const float* a1p = lh + (long)(row + 16)*H + kg*8;
            const float* a2p = lh + (long)(row + 32)*H + kg*8;
            const float* a3p = lh + (long)(row + 48)*H + kg*8;
            #pragma unroll
            for (int ks = 0; ks < 16; ks++){
                short8 bb = cvt8(Wp + ks*32);
                c0 = __builtin_amdgcn_mfma_f32_16x16x32_bf16(cvt8(a0p + ks*32), bb, c0, 0, 0, 0);
                c1 = __builtin_amdgcn_mfma_f32_16x16x32_bf16(cvt8(a1p + ks*32), bb, c1, 0, 0, 0);
                c2 = __builtin_amdgcn_mfma_f32_16x16x32_bf16(cvt8(a2p + ks*32), bb, c2, 0, 0, 0);
                c3 = __builtin_amdgcn_mfma_f32_16x16x32_bf16(cvt8(a3p + ks*32), bb, c3, 0, 0, 0);
            }
            float bh = bhh[j];
            #pragma unroll
            for (int r = 0; r < 4; r++){
                int bg = kg*4 + r;
                Gg[(long)(bg     )*G3 + j] = c0[r] + bh;
                Gg[(long)(bg + 16)*G3 + j] = c1[r] + bh;
                Gg[(long)(bg + 32)*G3 + j] = c2[r] + bh;
                Gg[(long)(bg + 48)*G3 + j] = c3[r] + bh;
            }
        }
    } else {
        const long n1 = (long)B*T*H/4, n2 = (long)B*T*S/4;
        const long nz = (long)B*EXT/4;
        long i0 = (long)(blockIdx.x - 96)*256 + threadIdx.x;
        long stride = 2048L*256;
        for (long i = i0; i < n1 + n2; i += stride){
            if (i < n1){
                long idx = i*4;
                int b = (int)(idx/(T*H)); int r = (int)(idx%(T*H)); int t = r/H; int k = r%H;
                *(f32x4*)(out + O_DECH + ((long)b*(T+1) + t)*H + k) = *(const f32x4*)(pdh + idx);
            } else {
                long idx = (i - n1)*4;
                int b = (int)(idx/(T*S)); int r = (int)(idx%(T*S)); int t = r/S; int s = r%S;
                *(f32x4*)(out + O_NPA + ((long)b*(T+1) + t)*S + s) = *(const f32x4*)(pa + idx);
            }
        }
        f32x4 z = {0.f,0.f,0.f,0.f};
        for (long i = i0; i < nz; i += stride)
            *(f32x4*)(tokd + i*4) = z;
    }
}

// ---------------- K2: fused = GRU recompute + enc att (blk<512) | dec att (blk>=512) ----------------
__global__ void __launch_bounds__(512) k_fused(const float* g, const float* Gg,
                        const float* lh, const float* wh, const float* wd,
                        const float* enc, const float* pa, const float* pdh,
                        float* ews, float* esum, float* encp, float* dec, float* out){
    __shared__ float sh[H];
    __shared__ float lacc[8][H];
    __shared__ float lsum[8];
    __shared__ float scs[64];
    int tid = threadIdx.x;
    if (blockIdx.x < 512){
        int b = blockIdx.x >> 3, c = blockIdx.x & 7;
        float hv = gru_h(g, Gg, lh, b, tid);
        sh[tid] = hv * wh[tid];
        if (c == 0){
            out[O_H + b*H + tid] = hv;
            out[O_DECH + ((long)b*(T+1) + T)*H + tid] = hv;
        }
        __syncthreads();
        int wave = tid >> 6, lane = tid & 63;
        f32x4 h0 = *(const f32x4*)(&sh[lane*8]);
        f32x4 h1 = *(const f32x4*)(&sh[lane*8 + 4]);
        float acc[8] = {0.f,0.f,0.f,0.f,0.f,0.f,0.f,0.f};
        float es = 0.f;
        for (int s0 = wave; s0 < S/NCE; s0 += 8){
            int s = c*(S/NCE) + s0;
            const float* ep = enc + ((long)b*S + s)*H + lane*8;
            f32x4 e0 = *(const f32x4*)(ep);
            f32x4 e1 = *(const f32x4*)(ep + 4);
            float d = 0.f;
            #pragma unroll
            for (int m = 0; m < 4; m++) d += h0[m]*e0[m] + h1[m]*e1[m];
            for (int off = 32; off > 0; off >>= 1) d += __shfl_xor(d, off);
            float pv = (lane < T) ? expf(pa[((long)b*T + lane)*S + s]) : 0.f;
            for (int off = 32; off > 0; off >>= 1) pv += __shfl_xor(pv, off);
            float ee = expf(d) / pv;
            if (lane == 0){
                out[O_NPA + ((long)b*(T+1) + T)*S + s] = d;
                ews[b*S + s] = ee;
            }
            es += ee;
            #pragma unroll
            for (int m = 0; m < 4; m++){ acc[m] += ee*e0[m]; acc[4+m] += ee*e1[m]; }
        }
        #pragma unroll
        for (int m = 0; m < 8; m++) lacc[wave][lane*8 + m] = acc[m];
        if (lane == 0) lsum[wave] = es;
        __syncthreads();
        float tt = 0.f;
        #pragma unroll
        for (int w = 0; w < 8; w++) tt += lacc[w][tid];
        encp[((long)b*NCE + c)*H + tid] = tt;
        if (tid == 0){
            float ss = 0.f;
            #pragma unroll
            for (int w = 0; w < 8; w++) ss += lsum[w];
            esum[b*NCE + c] = ss;
        }
    } else {
        int b = blockIdx.x - 512;
        float hv = gru_h(g, Gg, lh, b, tid);
        sh[tid] = hv * wd[tid];
        __syncthreads();
        int wave = tid >> 6, lane = tid & 63;
        f32x4 h0 = *(const f32x4*)(&sh[lane*8]);
        f32x4 h1 = *(const f32x4*)(&sh[lane*8 + 4]);
        for (int t = wave; t < T; t += 8){
            const float* pp = pdh + ((long)b*T + t)*H + lane*8;
            f32x4 p0 = *(const f32x4*)(pp);
            f32x4 p1 = *(const f32x4*)(pp + 4);
            float a = 0.f;
            #pragma unroll
            for (int m = 0; m < 4; m++) a += h0[m]*p0[m] + h1[m]*p1[m];
            for (int off = 32; off > 0; off >>= 1) a += __shfl_xor(a, off);
            if (lane == 0) scs[t] = a;
        }
        __syncthreads();
        if (wave == 0){
            float xv = (lane < T) ? scs[lane] : -1e30f;
            float m = xv;
            for (int off = 32; off > 0; off >>= 1) m = fmaxf(m, __shfl_xor(m, off));
            float e = (lane < T) ? expf(xv - m) : 0.f;
            float ssum = e;
            for (int off = 32; off > 0; off >>= 1) ssum += __shfl_xor(ssum, off);
            if (lane < T) scs[lane] = e / ssum;
        }
        __syncthreads();
        float a = 0.f;
        for (int t = 0; t < T; t++)
            a += scs[t] * pdh[((long)b*T + t)*H + tid];
        dec[b*H + tid] = a;
    }
}

// ---------------- K3: projcomb (swizzled projbf; et==0 pgen; et==1 att+scatter) ----------------
__global__ void k_projcomb(const float* g, const float* Gg, const float* lh,
                           const float* encp, const float* esum, const float* dec,
                           const float* Woh, const float* boh,
                           const float* Wgen, const float* bgen,
                           const float* ews, const int* fiv,
                           short* projbf, float* pg,
                           float* tokd, float* out){
    int blk = blockIdx.x;
    int b = blk >> 4, et = blk & 15;
    int tid = threadIdx.x;
    __shared__ float cl[G3];
    __shared__ float red[256];
    float inv = 0.f;
    #pragma unroll
    for (int c = 0; c < NCE; c++) inv += esum[b*NCE + c];
    inv = 1.f / inv;
    #pragma unroll
    for (int m = 0; m < 2; m++){
        int k = tid + 256*m;
        float hv = gru_h(g, Gg, lh, b, k);
        float v1 = 0.f;
        #pragma unroll
        for (int c = 0; c < NCE; c++) v1 += encp[(b*NCE + c)*H + k];
        cl[k] = hv; cl[H + k] = v1*inv; cl[2*H + k] = dec[b*H + k];
    }
    __syncthreads();
    int wave = tid >> 6, lane = tid & 63;
    int e0 = et*16 + wave*4;
    const float* w0 = Woh + (long)(e0+0)*G3;
    const float* w1 = Woh + (long)(e0+1)*G3;
    const float* w2 = Woh + (long)(e0+2)*G3;
    const float* w3 = Woh + (long)(e0+3)*G3;
    float a0=0.f, a1=0.f, a2=0.f, a3=0.f;
    #pragma unroll
    for (int m = 0; m < 24; m++){
        int idx = lane + 64*m;
        float c = cl[idx];
        a0 += c * w0[idx]; a1 += c * w1[idx];
        a2 += c * w2[idx]; a3 += c * w3[idx];
    }
    for (int off = 32; off > 0; off >>= 1){
        a0 += __shfl_xor(a0, off); a1 += __shfl_xor(a1, off);
        a2 += __shfl_xor(a2, off); a3 += __shfl_xor(a3, off);
    }
    if (lane == 0){
        projbf[pb_idx(b, e0+0)] = f2bs(a0 + boh[e0+0]);
        projbf[pb_idx(b, e0+1)] = f2bs(a1 + boh[e0+1]);
        projbf[pb_idx(b, e0+2)] = f2bs(a2 + boh[e0+2]);
        projbf[pb_idx(b, e0+3)] = f2bs(a3 + boh[e0+3]);
    }
    if (et == 0){
        float part = 0.f;
        #pragma unroll
        for (int m = 0; m < 6; m++){
            int j = tid + 256*m;
            part += cl[j] * Wgen[j];
        }
        red[tid] = part; __syncthreads();
        for (int off = 128; off > 0; off >>= 1){
            if (tid < off) red[tid] += red[tid + off];
            __syncthreads();
        }
        if (tid == 0){
            float pv = sigmoidf_(red[0] + bgen[0]);
            pg[b] = pv;
            out[O_PGEN + b] = pv;
        }
    } else if (et == 1){
        for (int s = tid; s < S; s += 256){
            float a = ews[b*S + s] * inv;
            out[O_ATT + b*S + s] = a;
            atomicAdd(&tokd[(long)b*EXT + fiv[b*S + s]], a);
        }
    }
}

// ---------------- K4 (cooperative): logits -> grid.sync -> smpart -> grid.sync -> final ----------------
// grid = 1024 x 256 (4 waves). Phase A: wave w runs task tau = w*1024 + bid
// (round-14 16-row logits task, wave-private LDS quadrant, swizzled projbf A).
// Phase B: block = (b, c) of NCH=16 exact V-chunks -> psum. Phase C: grid-stride final.
__global__ void __launch_bounds__(256, 4) k_tail(const short* projbf, const float* Wov,
                        const float* bov, float* psum, const float* pg,
                        const float* tokd, float* out){
    __shared__ short wb[4][16*264];
    __shared__ float red[256];
    cg::grid_group grid = cg::this_grid();
    int tid = threadIdx.x, bid = blockIdx.x;
    int wave = tid >> 6, lane = tid & 63;

    // ---- Phase A: logits MFMA ----
    int tau = wave*TGRID + bid;
    if (tau < V/16){
        int vbase = tau * 16;
        short* wq = &wb[wave][0];
        #pragma unroll 4
        for (int r = 0; r < 16; r++){
            f32x4 w = *(const f32x4*)(Wov + ((long)(vbase + r))*E + lane*4);
            short* d = &wq[r*264 + lane*4];
            d[0] = f2bs(w[0]); d[1] = f2bs(w[1]); d[2] = f2bs(w[2]); d[3] = f2bs(w[3]);
        }
        int row = lane & 15, kg = lane >> 4;
        f32x4 acc0 = {0.f,0.f,0.f,0.f}, acc1 = {0.f,0.f,0.f,0.f};
        f32x4 acc2 = {0.f,0.f,0.f,0.f}, acc3 = {0.f,0.f,0.f,0.f};
        const short* Bl = &wq[row*264 + kg*8];
        #pragma unroll
        for (int ks = 0; ks < 8; ks++){
            short8 bb = *(const short8*)(Bl + ks*32);
            short8 a0 = *(const short8*)(projbf + ((0*8 + ks)*64 + lane)*8);
            short8 a1 = *(const short8*)(projbf + ((1*8 + ks)*64 + lane)*8);
            short8 a2 = *(const short8*)(projbf + ((2*8 + ks)*64 + lane)*8);
            short8 a3 = *(const short8*)(projbf + ((3*8 + ks)*64 + lane)*8);
            acc0 = __builtin_amdgcn_mfma_f32_16x16x32_bf16(a0, bb, acc0, 0, 0, 0);
            acc1 = __builtin_amdgcn_mfma_f32_16x16x32_bf16(a1, bb, acc1, 0, 0, 0);
            acc2 = __builtin_amdgcn_mfma_f32_16x16x32_bf16(a2, bb, acc2, 0, 0, 0);
            acc3 = __builtin_amdgcn_mfma_f32_16x16x32_bf16(a3, bb, acc3, 0, 0, 0);
        }
        int v = vbase + row;
        float bv = bov[v];
        #pragma unroll
        for (int r = 0; r < 4; r++){
            int bg = kg*4 + r;
            out[O_PVOCAB + (long)(bg     )*V + v] = acc0[r] + bv;
            out[O_PVOCAB + (long)(bg + 16)*V + v] = acc1[r] + bv;
            out[O_PVOCAB + (long)(bg + 32)*V + v] = acc2[r] + bv;
            out[O_PVOCAB + (long)(bg + 48)*V + v] = acc3[r] + bv;
        }
    }
    grid.sync();

    // ---- Phase B: partial exp-sums (NCH=16 exact chunks of 3125) ----
    {
        int b = bid >> 4, c = bid & 15;
        const int chunk = V / NCH;   // 3125
        int start = c*chunk, end = start + chunk;
        float s = 0.f;
        for (int v = start + tid; v < end; v += 256)
            s += expf(out[O_PVOCAB + (long)b*V + v]);
        red[tid] = s; __syncthreads();
        for (int off = 128; off > 0; off >>= 1){
            if (tid < off) red[tid] += red[tid + off];
            __syncthreads();
        }
        if (tid == 0) psum[b*NCH + c] = red[0];
    }
    grid.sync();

    // ---- Phase C: p_vocab normalize + p_final (grid-stride) ----
    __shared__ float sums[64], pgs[64];
    if (tid < 64){
        float s = 0.f;
        #pragma unroll
        for (int c = 0; c < NCH; c++) s += psum[tid*NCH + c];
        sums[tid] = 1.f / s;
        pgs[tid] = pg[tid];
    }
    __syncthreads();
    const int total = B*EXT;
    for (int i = bid*256 + tid; i < total; i += TGRID*256){
        int b = i / EXT, t = i - b*EXT;
        float gv = pgs[b];
        float td = tokd[(long)b*EXT + t];
        float pf;
        if (t < V){
            long idx = O_PVOCAB + (long)b*V + t;
            float pv = expf(out[idx]) * sums[b];
            out[idx] = pv;
            pf = pv*gv + (1.f - gv)*td;
        } else {
            pf = (1.f - gv)*td;
        }
        out[O_PFINAL + (long)b*EXT + t] = pf;
    }
}

extern "C" void kernel_launch(void* const* d_in, const int* in_sizes, int n_in,
                              void* d_out, int out_size, void* d_ws, size_t ws_size,
                              hipStream_t stream) {
    const int*   tok  = (const int*)d_in[0];
    const float* pdh  = (const float*)d_in[1];
    const float* lh   = (const float*)d_in[2];
    const float* enc  = (const float*)d_in[3];
    const int*   fiv  = (const int*)d_in[4];
    const float* pa   = (const float*)d_in[5];
    const float* emb  = (const float*)d_in[7];
    const float* Wih  = (const float*)d_in[8];
    const float* Whh  = (const float*)d_in[9];
    const float* bih  = (const float*)d_in[10];
    const float* bhh  = (const float*)d_in[11];
    const float* wh   = (const float*)d_in[12];
    const float* wd   = (const float*)d_in[13];
    const float* Woh  = (const float*)d_in[14];
    const float* boh  = (const float*)d_in[15];
    const float* Wov  = (const float*)d_in[16];
    const float* bov  = (const float*)d_in[17];
    const float* Wgen = (const float*)d_in[18];
    const float* bgen = (const float*)d_in[19];

    float* ws  = (float*)d_ws;
    float* out = (float*)d_out;

    float* g      = ws + OFF_G;
    float* Gg     = ws + OFF_GG;
    float* encp   = ws + OFF_ENCP;
    float* dec    = ws + OFF_DEC;
    float* ews    = ws + OFF_E;
    float* esum   = ws + OFF_ESUM;
    float* pg     = ws + OFF_PG;
    short* projbf = (short*)(ws + OFF_PROJBF);
    float* psum   = ws + OFF_PSUM;
    float* tokd   = ws + OFF_TOK;

    k_front   <<<96 + 2048, 256, 0, stream>>>(tok, emb, lh, Wih, Whh, bih, bhh,
                                              pdh, pa, g, Gg, out, tokd);
    k_fused   <<<512 + 64, 512, 0, stream>>>(g, Gg, lh, wh, wd, enc, pa, pdh,
                                             ews, esum, encp, dec, out);
    k_projcomb<<<B*16, 256, 0, stream>>>(g, Gg, lh, encp, esum, dec,
                                         Woh, boh, Wgen, bgen, ews, fiv,
                                         projbf, pg, tokd, out);
    {
        const short* projbf_c = projbf;
        const float* pg_c = pg;
        const float* tokd_c = tokd;
        void* args[] = { (void*)&projbf_c, (void*)&Wov, (void*)&bov,
                         (void*)&psum, (void*)&pg_c, (void*)&tokd_c, (void*)&out };
        hipLaunchCooperativeKernel((void*)k_tail, dim3(TGRID), dim3(256),
                                   args, 0, stream);
    }
}

// Round 16
// 73.158 us; speedup vs baseline: 4.1687x; 4.1687x over previous
//
#include <hip/hip_runtime.h>
#include <hip/hip_bf16.h>

#define B 64
#define T 50
#define S 400
#define H 512
#define E 256
#define V 50000
#define EXT 50250
#define G3 1536
#define NCH 32
#define NCE 8

typedef __attribute__((ext_vector_type(8))) short short8;
typedef __attribute__((ext_vector_type(4))) float f32x4;

// ---- output offsets (f32 elements, return order) ----
#define O_PFINAL 0L
#define O_PGEN   3216000L
#define O_PVOCAB 3216064L
#define O_ATT    6416064L
#define O_DECH   6441664L
#define O_H      8112832L
#define O_NPA    8145600L

// ---- workspace offsets (f32 elements); ws = 256 MB ----
#define OFF_G      0L        /* B*G3 = 98304 */
#define OFF_GG     98304L    /* B*G3 */
#define OFF_ENCP   196608L   /* B*NCE*H = 262144 */
#define OFF_DEC    458752L   /* B*H */
#define OFF_E      491520L   /* B*S */
#define OFF_ESUM   517120L   /* B*NCE */
#define OFF_PG     517632L   /* 64 */
#define OFF_PROJBF 517696L   /* 16384 bf16 = 8192 f32 */
#define OFF_PSUM   525888L   /* B*NCH = 2048 */
#define OFF_TOK    1048576L  /* B*EXT f32 */

__device__ __forceinline__ float sigmoidf_(float x){ return 1.0f/(1.0f+expf(-x)); }
__device__ __forceinline__ short f2bs(float x){
    union { __hip_bfloat16 b; short s; } c; c.b = __float2bfloat16(x); return c.s;
}
__device__ __forceinline__ short8 cvt8(const float* p){
    f32x4 w0 = *(const f32x4*)p;
    f32x4 w1 = *(const f32x4*)(p + 4);
    short8 r;
    r[0]=f2bs(w0[0]); r[1]=f2bs(w0[1]); r[2]=f2bs(w0[2]); r[3]=f2bs(w0[3]);
    r[4]=f2bs(w1[0]); r[5]=f2bs(w1[1]); r[6]=f2bs(w1[2]); r[7]=f2bs(w1[3]);
    return r;
}
// swizzled projbf index: store in MFMA A-fragment order so k_logits A-loads
// are coalesced. (b,e) -> ((chain*8 + ks)*4 + kg)*128 + row*8 + j
// chain=b>>4, row=b&15, ks=e>>5, kg=(e>>3)&3, j=e&7.  Bijective on [0,16384).
__device__ __forceinline__ int pb_idx(int b, int e){
    return ((((b >> 4)*8 + (e >> 5))*4 + ((e >> 3) & 3))*16 + (b & 15))*8 + (e & 7);
}
// GRU recompute for one (b,k): deterministic, identical everywhere it's used
__device__ __forceinline__ float gru_h(const float* g, const float* Gg,
                                       const float* lh, int b, int k){
    float ir = g [b*G3 + k], iz = g [b*G3 + H + k], inn = g [b*G3 + 2*H + k];
    float hr = Gg[b*G3 + k], hz = Gg[b*G3 + H + k], hn  = Gg[b*G3 + 2*H + k];
    float r = sigmoidf_(ir + hr), z = sigmoidf_(iz + hz);
    float n = tanhf(inn + r*hn);
    return (1.f - z)*n + z*lh[b*H + k];
}

// ---------------- K1: front = gates MFMA (blk<96) | copies+zero (blk>=96) ----------------
__global__ void __launch_bounds__(256) k_front(const int* tok,
                        const float* emb, const float* lh,
                        const float* Wih, const float* Whh,
                        const float* bih, const float* bhh,
                        const float* pdh, const float* pa,
                        float* g, float* Gg, float* out, float* tokd){
    if (blockIdx.x < 96){
        if (threadIdx.x >= 128) return;
        int lane = threadIdx.x & 63, wave = threadIdx.x >> 6;
        int row = lane & 15, kg = lane >> 4;
        int j = blockIdx.x*16 + row;
        f32x4 c0={0.f,0.f,0.f,0.f}, c1={0.f,0.f,0.f,0.f};
        f32x4 c2={0.f,0.f,0.f,0.f}, c3={0.f,0.f,0.f,0.f};
        if (wave == 0){
            const float* Wp = Wih + (long)j*E + kg*8;
            const float* a0p = emb + (long)tok[row     ]*E + kg*8;
            const float* a1p = emb + (long)tok[row + 16]*E + kg*8;
            const float* a2p = emb + (long)tok[row + 32]*E + kg*8;
            const float* a3p = emb + (long)tok[row + 48]*E + kg*8;
            #pragma unroll
            for (int ks = 0; ks < 8; ks++){
                short8 bb = cvt8(Wp + ks*32);
                c0 = __builtin_amdgcn_mfma_f32_16x16x32_bf16(cvt8(a0p + ks*32), bb, c0, 0, 0, 0);
                c1 = __builtin_amdgcn_mfma_f32_16x16x32_bf16(cvt8(a1p + ks*32), bb, c1, 0, 0, 0);
                c2 = __builtin_amdgcn_mfma_f32_16x16x32_bf16(cvt8(a2p + ks*32), bb, c2, 0, 0, 0);
                c3 = __builtin_amdgcn_mfma_f32_16x16x32_bf16(cvt8(a3p + ks*32), bb, c3, 0, 0, 0);
            }
            float bi = bih[j];
            #pragma unroll
            for (int r = 0; r < 4; r++){
                int bg = kg*4 + r;
                g[(long)(bg     )*G3 + j] = c0[r] + bi;
                g[(long)(bg + 16)*G3 + j] = c1[r] + bi;
                g[(long)(bg + 32)*G3 + j] = c2[r] + bi;
                g[(long)(bg + 48)*G3 + j] = c3[r] + bi;
            }
        } else {
            const float* Wp = Whh + (long)j*H + kg*8;
            const float* a0p = lh + (long)(row     )*H + kg*8;
            const float* a1p = lh + (long)(row + 16)*H + kg*8;
            const float* a2p = lh + (long)(row + 32)*H + kg*8;
            const float* a3p = lh + (long)(row + 48)*H + kg*8;
            #pragma unroll
            for (int ks = 0; ks < 16; ks++){
                short8 bb = cvt8(Wp + ks*32);
                c0 = __builtin_amdgcn_mfma_f32_16x16x32_bf16(cvt8(a0p + ks*32), bb, c0, 0, 0, 0);
                c1 = __builtin_amdgcn_mfma_f32_16x16x32_bf16(cvt8(a1p + ks*32), bb, c1, 0, 0, 0);
                c2 = __builtin_amdgcn_mfma_f32_16x16x32_bf16(cvt8(a2p + ks*32), bb, c2, 0, 0, 0);
                c3 = __builtin_amdgcn_mfma_f32_16x16x32_bf16(cvt8(a3p + ks*32), bb, c3, 0, 0, 0);
            }
            float bh = bhh[j];
            #pragma unroll
            for (int r = 0; r < 4; r++){
                int bg = kg*4 + r;
                Gg[(long)(bg     )*G3 + j] = c0[r] + bh;
                Gg[(long)(bg + 16)*G3 + j] = c1[r] + bh;
                Gg[(long)(bg + 32)*G3 + j] = c2[r] + bh;
                Gg[(long)(bg + 48)*G3 + j] = c3[r] + bh;
            }
        }
    } else {
        const long n1 = (long)B*T*H/4, n2 = (long)B*T*S/4;
        const long nz = (long)B*EXT/4;
        long i0 = (long)(blockIdx.x - 96)*256 + threadIdx.x;
        long stride = 2048L*256;
        for (long i = i0; i < n1 + n2; i += stride){
            if (i < n1){
                long idx = i*4;
                int b = (int)(idx/(T*H)); int r = (int)(idx%(T*H)); int t = r/H; int k = r%H;
                *(f32x4*)(out + O_DECH + ((long)b*(T+1) + t)*H + k) = *(const f32x4*)(pdh + idx);
            } else {
                long idx = (i - n1)*4;
                int b = (int)(idx/(T*S)); int r = (int)(idx%(T*S)); int t = r/S; int s = r%S;
                *(f32x4*)(out + O_NPA + ((long)b*(T+1) + t)*S + s) = *(const f32x4*)(pa + idx);
            }
        }
        f32x4 z = {0.f,0.f,0.f,0.f};
        for (long i = i0; i < nz; i += stride)
            *(f32x4*)(tokd + i*4) = z;
    }
}

// ---------------- K2: fused = GRU recompute + enc att (blk<512) | dec att (blk>=512) ----------------
__global__ void __launch_bounds__(512) k_fused(const float* g, const float* Gg,
                        const float* lh, const float* wh, const float* wd,
                        const float* enc, const float* pa, const float* pdh,
                        float* ews, float* esum, float* encp, float* dec, float* out){
    __shared__ float sh[H];          // hw (enc path) or hwd (dec path)
    __shared__ float lacc[8][H];
    __shared__ float lsum[8];
    __shared__ float scs[64];
    int tid = threadIdx.x;
    if (blockIdx.x < 512){
        int b = blockIdx.x >> 3, c = blockIdx.x & 7;
        float hv = gru_h(g, Gg, lh, b, tid);
        sh[tid] = hv * wh[tid];
        if (c == 0){
            out[O_H + b*H + tid] = hv;
            out[O_DECH + ((long)b*(T+1) + T)*H + tid] = hv;
        }
        __syncthreads();
        int wave = tid >> 6, lane = tid & 63;
        f32x4 h0 = *(const f32x4*)(&sh[lane*8]);
        f32x4 h1 = *(const f32x4*)(&sh[lane*8 + 4]);
        float acc[8] = {0.f,0.f,0.f,0.f,0.f,0.f,0.f,0.f};
        float es = 0.f;
        for (int s0 = wave; s0 < S/NCE; s0 += 8){
            int s = c*(S/NCE) + s0;
            const float* ep = enc + ((long)b*S + s)*H + lane*8;
            f32x4 e0 = *(const f32x4*)(ep);
            f32x4 e1 = *(const f32x4*)(ep + 4);
            float d = 0.f;
            #pragma unroll
            for (int m = 0; m < 4; m++) d += h0[m]*e0[m] + h1[m]*e1[m];
            for (int off = 32; off > 0; off >>= 1) d += __shfl_xor(d, off);
            float pv = (lane < T) ? expf(pa[((long)b*T + lane)*S + s]) : 0.f;
            for (int off = 32; off > 0; off >>= 1) pv += __shfl_xor(pv, off);
            float ee = expf(d) / pv;
            if (lane == 0){
                out[O_NPA + ((long)b*(T+1) + T)*S + s] = d;
                ews[b*S + s] = ee;
            }
            es += ee;
            #pragma unroll
            for (int m = 0; m < 4; m++){ acc[m] += ee*e0[m]; acc[4+m] += ee*e1[m]; }
        }
        #pragma unroll
        for (int m = 0; m < 8; m++) lacc[wave][lane*8 + m] = acc[m];
        if (lane == 0) lsum[wave] = es;
        __syncthreads();
        float tt = 0.f;
        #pragma unroll
        for (int w = 0; w < 8; w++) tt += lacc[w][tid];
        encp[((long)b*NCE + c)*H + tid] = tt;
        if (tid == 0){
            float ss = 0.f;
            #pragma unroll
            for (int w = 0; w < 8; w++) ss += lsum[w];
            esum[b*NCE + c] = ss;
        }
    } else {
        int b = blockIdx.x - 512;
        float hv = gru_h(g, Gg, lh, b, tid);
        sh[tid] = hv * wd[tid];
        __syncthreads();
        int wave = tid >> 6, lane = tid & 63;
        f32x4 h0 = *(const f32x4*)(&sh[lane*8]);
        f32x4 h1 = *(const f32x4*)(&sh[lane*8 + 4]);
        for (int t = wave; t < T; t += 8){
            const float* pp = pdh + ((long)b*T + t)*H + lane*8;
            f32x4 p0 = *(const f32x4*)(pp);
            f32x4 p1 = *(const f32x4*)(pp + 4);
            float a = 0.f;
            #pragma unroll
            for (int m = 0; m < 4; m++) a += h0[m]*p0[m] + h1[m]*p1[m];
            for (int off = 32; off > 0; off >>= 1) a += __shfl_xor(a, off);
            if (lane == 0) scs[t] = a;
        }
        __syncthreads();
        if (wave == 0){
            float xv = (lane < T) ? scs[lane] : -1e30f;
            float m = xv;
            for (int off = 32; off > 0; off >>= 1) m = fmaxf(m, __shfl_xor(m, off));
            float e = (lane < T) ? expf(xv - m) : 0.f;
            float ssum = e;
            for (int off = 32; off > 0; off >>= 1) ssum += __shfl_xor(ssum, off);
            if (lane < T) scs[lane] = e / ssum;
        }
        __syncthreads();
        float a = 0.f;
        for (int t = 0; t < T; t++)
            a += scs[t] * pdh[((long)b*T + t)*H + tid];
        dec[b*H + tid] = a;
    }
}

// ---------------- K3: projcomb = comb(GRU recompute) + proj GEMM + extras ----------------
// et==0: p_gen; et==1: att finalize + scatter
// projbf written in SWIZZLED A-fragment order (pb_idx) for coalesced k_logits loads.
__global__ void k_projcomb(const float* g, const float* Gg, const float* lh,
                           const float* encp, const float* esum, const float* dec,
                           const float* Woh, const float* boh,
                           const float* Wgen, const float* bgen,
                           const float* ews, const int* fiv,
                           short* projbf, float* pg,
                           float* tokd, float* out){
    int blk = blockIdx.x;
    int b = blk >> 4, et = blk & 15;
    int tid = threadIdx.x;
    __shared__ float cl[G3];
    __shared__ float red[256];
    float inv = 0.f;
    #pragma unroll
    for (int c = 0; c < NCE; c++) inv += esum[b*NCE + c];
    inv = 1.f / inv;
    #pragma unroll
    for (int m = 0; m < 2; m++){
        int k = tid + 256*m;
        float hv = gru_h(g, Gg, lh, b, k);
        float v1 = 0.f;
        #pragma unroll
        for (int c = 0; c < NCE; c++) v1 += encp[(b*NCE + c)*H + k];
        cl[k] = hv; cl[H + k] = v1*inv; cl[2*H + k] = dec[b*H + k];
    }
    __syncthreads();
    int wave = tid >> 6, lane = tid & 63;
    int e0 = et*16 + wave*4;
    const float* w0 = Woh + (long)(e0+0)*G3;
    const float* w1 = Woh + (long)(e0+1)*G3;
    const float* w2 = Woh + (long)(e0+2)*G3;
    const float* w3 = Woh + (long)(e0+3)*G3;
    float a0=0.f, a1=0.f, a2=0.f, a3=0.f;
    #pragma unroll
    for (int m = 0; m < 24; m++){
        int idx = lane + 64*m;
        float c = cl[idx];
        a0 += c * w0[idx]; a1 += c * w1[idx];
        a2 += c * w2[idx]; a3 += c * w3[idx];
    }
    for (int off = 32; off > 0; off >>= 1){
        a0 += __shfl_xor(a0, off); a1 += __shfl_xor(a1, off);
        a2 += __shfl_xor(a2, off); a3 += __shfl_xor(a3, off);
    }
    if (lane == 0){
        projbf[pb_idx(b, e0+0)] = f2bs(a0 + boh[e0+0]);
        projbf[pb_idx(b, e0+1)] = f2bs(a1 + boh[e0+1]);
        projbf[pb_idx(b, e0+2)] = f2bs(a2 + boh[e0+2]);
        projbf[pb_idx(b, e0+3)] = f2bs(a3 + boh[e0+3]);
    }
    if (et == 0){
        float part = 0.f;
        #pragma unroll
        for (int m = 0; m < 6; m++){
            int j = tid + 256*m;
            part += cl[j] * Wgen[j];
        }
        red[tid] = part; __syncthreads();
        for (int off = 128; off > 0; off >>= 1){
            if (tid < off) red[tid] += red[tid + off];
            __syncthreads();
        }
        if (tid == 0){
            float pv = sigmoidf_(red[0] + bgen[0]);
            pg[b] = pv;
            out[O_PGEN + b] = pv;
        }
    } else if (et == 1){
        for (int s = tid; s < S; s += 256){
            float a = ews[b*S + s] * inv;
            out[O_ATT + b*S + s] = a;
            atomicAdd(&tokd[(long)b*EXT + fiv[b*S + s]], a);
        }
    }
}

// ---------------- K4: logits MFMA, LDS-staged Wov + swizzled (coalesced) projbf ----------------
// grid = V/16 = 3125 blocks, 64 thr. Round-12 structure (high block parallelism).
__global__ void __launch_bounds__(64) k_logits(const short* projbf, const float* Wov,
                         const float* bov, float* out){
    __shared__ short wb[16*264];
    int lane = threadIdx.x;
    int vbase = blockIdx.x * 16;
    #pragma unroll 4
    for (int r = 0; r < 16; r++){
        f32x4 w = *(const f32x4*)(Wov + ((long)(vbase + r))*E + lane*4);
        short* d = &wb[r*264 + lane*4];
        d[0] = f2bs(w[0]); d[1] = f2bs(w[1]); d[2] = f2bs(w[2]); d[3] = f2bs(w[3]);
    }
    __syncthreads();
    int row = lane & 15, kg = lane >> 4;
    f32x4 acc0 = {0.f,0.f,0.f,0.f}, acc1 = {0.f,0.f,0.f,0.f};
    f32x4 acc2 = {0.f,0.f,0.f,0.f}, acc3 = {0.f,0.f,0.f,0.f};
    const short* Bl = &wb[row*264 + kg*8];
    #pragma unroll
    for (int ks = 0; ks < 8; ks++){
        short8 bb = *(const short8*)(Bl + ks*32);
        // swizzled layout: chain N, slice ks -> base (N*8+ks)*64*8, lane-contiguous
        short8 a0 = *(const short8*)(projbf + ((0*8 + ks)*64 + lane)*8);
        short8 a1 = *(const short8*)(projbf + ((1*8 + ks)*64 + lane)*8);
        short8 a2 = *(const short8*)(projbf + ((2*8 + ks)*64 + lane)*8);
        short8 a3 = *(const short8*)(projbf + ((3*8 + ks)*64 + lane)*8);
        acc0 = __builtin_amdgcn_mfma_f32_16x16x32_bf16(a0, bb, acc0, 0, 0, 0);
        acc1 = __builtin_amdgcn_mfma_f32_16x16x32_bf16(a1, bb, acc1, 0, 0, 0);
        acc2 = __builtin_amdgcn_mfma_f32_16x16x32_bf16(a2, bb, acc2, 0, 0, 0);
        acc3 = __builtin_amdgcn_mfma_f32_16x16x32_bf16(a3, bb, acc3, 0, 0, 0);
    }
    int v = vbase + row;
    float bv = bov[v];
    #pragma unroll
    for (int r = 0; r < 4; r++){
        int bg = kg*4 + r;
        out[O_PVOCAB + (long)(bg     )*V + v] = acc0[r] + bv;
        out[O_PVOCAB + (long)(bg + 16)*V + v] = acc1[r] + bv;
        out[O_PVOCAB + (long)(bg + 32)*V + v] = acc2[r] + bv;
        out[O_PVOCAB + (long)(bg + 48)*V + v] = acc3[r] + bv;
    }
}

// ---------------- K5: partial exp-sum (logits bounded; no max needed) ----------------
__global__ void k_smpart(const float* logits, float* psum){
    int b = blockIdx.x / NCH, c = blockIdx.x % NCH;
    const int chunk = (V + NCH - 1)/NCH;
    int start = c*chunk;
    int end = start + chunk; if (end > V) end = V;
    float s = 0.f;
    for (int v = start + threadIdx.x; v < end; v += 256)
        s += expf(logits[(long)b*V + v]);
    __shared__ float ss[256];
    int tid = threadIdx.x;
    ss[tid] = s; __syncthreads();
    for (int off = 128; off > 0; off >>= 1){
        if (tid < off) ss[tid] += ss[tid + off];
        __syncthreads();
    }
    if (tid == 0) psum[blockIdx.x] = ss[0];
}

// ---------------- K6: p_vocab + p_final ----------------
__global__ void k_final(const float* psum, const float* pg,
                        const float* tokd, float* out){
    __shared__ float sm[1];
    int b = blockIdx.y;
    if (threadIdx.x < 64){
        int lane = threadIdx.x;
        float s = (lane < NCH) ? psum[b*NCH + lane] : 0.f;
        for (int off = 32; off > 0; off >>= 1) s += __shfl_xor(s, off);
        if (lane == 0) sm[0] = s;
    }
    __syncthreads();
    float inv = 1.f / sm[0];
    int t = blockIdx.x*256 + threadIdx.x;
    if (t >= EXT) return;
    float gv = pg[b];
    float td = tokd[(long)b*EXT + t];
    float pf;
    if (t < V){
        long idx = O_PVOCAB + (long)b*V + t;
        float pv = expf(out[idx]) * inv;
        out[idx] = pv;
        pf = pv*gv + (1.f - gv)*td;
    } else {
        pf = (1.f - gv)*td;
    }
    out[O_PFINAL + (long)b*EXT + t] = pf;
}

extern "C" void kernel_launch(void* const* d_in, const int* in_sizes, int n_in,
                              void* d_out, int out_size, void* d_ws, size_t ws_size,
                              hipStream_t stream) {
    const int*   tok  = (const int*)d_in[0];
    const float* pdh  = (const float*)d_in[1];
    const float* lh   = (const float*)d_in[2];
    const float* enc  = (const float*)d_in[3];
    const int*   fiv  = (const int*)d_in[4];
    const float* pa   = (const float*)d_in[5];
    const float* emb  = (const float*)d_in[7];
    const float* Wih  = (const float*)d_in[8];
    const float* Whh  = (const float*)d_in[9];
    const float* bih  = (const float*)d_in[10];
    const float* bhh  = (const float*)d_in[11];
    const float* wh   = (const float*)d_in[12];
    const float* wd   = (const float*)d_in[13];
    const float* Woh  = (const float*)d_in[14];
    const float* boh  = (const float*)d_in[15];
    const float* Wov  = (const float*)d_in[16];
    const float* bov  = (const float*)d_in[17];
    const float* Wgen = (const float*)d_in[18];
    const float* bgen = (const float*)d_in[19];

    float* ws  = (float*)d_ws;
    float* out = (float*)d_out;

    float* g      = ws + OFF_G;
    float* Gg     = ws + OFF_GG;
    float* encp   = ws + OFF_ENCP;
    float* dec    = ws + OFF_DEC;
    float* ews    = ws + OFF_E;
    float* esum   = ws + OFF_ESUM;
    float* pg     = ws + OFF_PG;
    short* projbf = (short*)(ws + OFF_PROJBF);
    float* psum   = ws + OFF_PSUM;
    float* tokd   = ws + OFF_TOK;

    k_front   <<<96 + 2048, 256, 0, stream>>>(tok, emb, lh, Wih, Whh, bih, bhh,
                                              pdh, pa, g, Gg, out, tokd);
    k_fused   <<<512 + 64, 512, 0, stream>>>(g, Gg, lh, wh, wd, enc, pa, pdh,
                                             ews, esum, encp, dec, out);
    k_projcomb<<<B*16, 256, 0, stream>>>(g, Gg, lh, encp, esum, dec,
                                         Woh, boh, Wgen, bgen, ews, fiv,
                                         projbf, pg, tokd, out);
    k_logits  <<<V/16, 64, 0, stream>>>(projbf, Wov, bov, out);
    k_smpart  <<<B*NCH, 256, 0, stream>>>(out + O_PVOCAB, psum);
    {
        dim3 grid((EXT + 255)/256, B);
        k_final<<<grid, 256, 0, stream>>>(psum, pg, tokd, out);
    }
}